// Round 1
// baseline (346.686 us; speedup 1.0000x reference)
//
#include <hip/hip_runtime.h>
#include <math.h>

#define BSZ 2
#define NPOINT 128
#define NPTS 8192
#define CH_F 128
#define HEAD_BINS 12
#define KCOR 64
#define MTOT (NPOINT*KCOR)   /* 8192 corners per batch */
#define NCH 8
#define CHUNK (NPTS/NCH)     /* 1024 */
#define FEAT_C 131
#define MLP2_C 256

/* ---- workspace byte offsets (all 256-aligned), total ~21.6 MB ---- */
#define OFF_CORNERS 0u
#define OFF_REL     196608u
#define OFF_PD      393216u      /* partial d2: 2*8192*8*3 f32 */
#define OFF_PI      1966080u     /* partial idx */
#define OFF_IDX     3538944u     /* final idx3 */
#define OFF_W3      3735552u     /* final weights */
#define OFF_FEATT   3932160u     /* [2][8192][128] */
#define OFF_FEAT    12320768u    /* [2][8192][131] */
#define OFF_W1T     20905984u    /* [131][128] */
#define OFF_W2T     20973056u    /* [128][256] */
#define OFF_H2      21104128u    /* [2][256][128] */
#define OFF_X0      21366272u
#define OFF_X1      21497344u
#define OFF_BN0     21628416u    /* scale[128], shift[128] */
#define OFF_BN1     21629440u

/* ---------------- decode: heading/center/lwh -> corners + rel ------------- */
__global__ void k_decode(const float* __restrict__ cand, const float* __restrict__ offs,
                         const float* __restrict__ angc, const float* __restrict__ angr,
                         float* __restrict__ corners, float* __restrict__ rel)
{
    int t = threadIdx.x;
    int b = t >> 7, p = t & 127;
    int bp = b*NPOINT + p;
    const float* ac = angc + bp*HEAD_BINS;
    int best = 0; float bv = ac[0];
    #pragma unroll
    for (int j = 1; j < HEAD_BINS; ++j) { float v = ac[j]; if (v > bv) { bv = v; best = j; } }
    float ares = angr[bp*HEAD_BINS + best];
    float angle = (float)best * 0.52359877559829882f + ares;
    float heading = (angle > 3.14159265358979323f) ? (angle - 6.28318530717958647f) : angle;
    float cx = cand[bp*3+0] + offs[bp*6+0];
    float cy = cand[bp*3+1] + offs[bp*6+1];
    float cz = cand[bp*3+2] + offs[bp*6+2];
    float dl = fmaxf(offs[bp*6+3]*2.0f, 0.1f);
    float dw = fmaxf(offs[bp*6+4]*2.0f, 0.1f);
    float dh = fmaxf(offs[bp*6+5]*2.0f, 0.1f);
    float chd = cosf(heading), shd = sinf(heading);
    for (int k = 0; k < KCOR; ++k) {
        int ix = (k>>4)&3, iy = (k>>2)&3, iz = k&3;
        /* linspace(-1,1,4) with exact endpoint like numpy */
        float gx = (ix==3) ? 1.0f : (-1.0f + (2.0f/3.0f)*(float)ix);
        float gy = (iy==3) ? 1.0f : (-1.0f + (2.0f/3.0f)*(float)iy);
        float gz = (iz==3) ? 1.0f : (-1.0f + (2.0f/3.0f)*(float)iz);
        float wx = gx*dl, wy = gy*dw, wz = gz*dh;
        float rx = wx*chd - wy*shd;
        float ry = wx*shd + wy*chd;
        size_t base = ((size_t)b*MTOT + p*KCOR + k)*3;
        rel[base+0] = rx; rel[base+1] = ry; rel[base+2] = wz;
        corners[base+0] = rx + cx; corners[base+1] = ry + cy; corners[base+2] = wz + cz;
    }
}

/* ---------------- weight transposes ---------------- */
__global__ void k_prepw(const float* __restrict__ w1, const float* __restrict__ w2,
                        float* __restrict__ w1t, float* __restrict__ w2t)
{
    int t = blockIdx.x*256 + threadIdx.x;
    int stride = gridDim.x*256;
    for (int i = t; i < FEAT_C*128; i += stride) { int o = i & 127, c = i >> 7; w1t[i] = w1[o*FEAT_C + c]; }
    for (int i = t; i < 128*256;    i += stride) { int o = i & 255, c = i >> 8; w2t[i] = w2[o*128 + c]; }
}

/* ---------------- transpose original_feature [C][N] -> [N][C] ------------- */
__global__ __launch_bounds__(256) void k_transpose(const float* __restrict__ of, float* __restrict__ ft)
{
    __shared__ float tile[128][65];
    int b = blockIdx.y;
    int n0 = blockIdx.x * 64;
    int t = threadIdx.x;
    int r = t >> 6, col = t & 63;
    for (int c = r; c < 128; c += 4)
        tile[c][col] = of[((size_t)b*CH_F + c)*NPTS + n0 + col];
    __syncthreads();
    int cw = t & 127, nb = t >> 7;
    for (int n = nb; n < 64; n += 2)
        ft[((size_t)b*NPTS + n0 + n)*CH_F + cw] = tile[cw][n];
}

/* ---------------- three_nn partial: per-chunk top-3 ---------------- */
__global__ __launch_bounds__(256) void k_three_nn(const float* __restrict__ xyz,
        const float* __restrict__ corners, float* __restrict__ pd, int* __restrict__ pix)
{
    __shared__ float4 pts[CHUNK];
    int mb = blockIdx.x;   /* 0..31 */
    int ch = blockIdx.y;   /* 0..7  */
    int b  = blockIdx.z;   /* 0..1  */
    int t = threadIdx.x;

    const float4* s4 = (const float4*)(xyz + ((size_t)b*NPTS + (size_t)ch*CHUNK)*3);
    float4 a0 = s4[t*3+0], a1 = s4[t*3+1], a2 = s4[t*3+2];
    pts[t*4+0] = make_float4(a0.x, a0.y, a0.z, (a0.x*a0.x + a0.y*a0.y) + a0.z*a0.z);
    pts[t*4+1] = make_float4(a0.w, a1.x, a1.y, (a0.w*a0.w + a1.x*a1.x) + a1.y*a1.y);
    pts[t*4+2] = make_float4(a1.z, a1.w, a2.x, (a1.z*a1.z + a1.w*a1.w) + a2.x*a2.x);
    pts[t*4+3] = make_float4(a2.y, a2.z, a2.w, (a2.y*a2.y + a2.z*a2.z) + a2.w*a2.w);
    __syncthreads();

    int m = mb*256 + t;
    const float* cp = corners + ((size_t)b*MTOT + m)*3;
    float cx = cp[0], cy = cp[1], cz = cp[2];
    float sc = (cx*cx + cy*cy) + cz*cz;
    float s0 = 3.4e38f, s1 = 3.4e38f, s2 = 3.4e38f;
    int i0 = 0, i1 = 0, i2 = 0;
    #pragma unroll 4
    for (int n = 0; n < CHUNK; ++n) {
        float4 P = pts[n];                       /* broadcast LDS read */
        float dot = fmaf(cz, P.z, fmaf(cy, P.y, cx*P.x));
        float d2 = (sc + P.w) - 2.0f*dot;        /* matches ref formula */
        bool lt0 = d2 < s0, lt1 = d2 < s1, lt2 = d2 < s2;   /* strict: ties keep lower idx */
        s2 = lt1 ? s1 : (lt2 ? d2 : s2);
        i2 = lt1 ? i1 : (lt2 ? n  : i2);
        s1 = lt0 ? s0 : (lt1 ? d2 : s1);
        i1 = lt0 ? i0 : (lt1 ? n  : i1);
        s0 = lt0 ? d2 : s0;
        i0 = lt0 ? n  : i0;
    }
    int nb = ch*CHUNK;
    size_t ob = (((size_t)b*MTOT + m)*NCH + ch)*3;
    pd[ob+0] = s0; pd[ob+1] = s1; pd[ob+2] = s2;
    pix[ob+0] = nb+i0; pix[ob+1] = nb+i1; pix[ob+2] = nb+i2;
}

/* ---------------- merge partials + interpolation weights ---------------- */
__global__ void k_merge(const float* __restrict__ xyz, const float* __restrict__ corners,
                        const float* __restrict__ pd, const int* __restrict__ pix,
                        int* __restrict__ idx3, float* __restrict__ w3)
{
    int f = blockIdx.x*256 + threadIdx.x;  /* 0..16383 : b*8192+m */
    int b = f >> 13;
    float s0=3.4e38f, s1=3.4e38f, s2=3.4e38f;
    int i0=0x7fffffff, i1=0x7fffffff, i2=0x7fffffff;
    size_t base = (size_t)f * (NCH*3);
    for (int c = 0; c < NCH*3; ++c) {
        float d = pd[base+c]; int id = pix[base+c];
        bool lt0 = (d < s0) || (d == s0 && id < i0);
        bool lt1 = (d < s1) || (d == s1 && id < i1);
        bool lt2 = (d < s2) || (d == s2 && id < i2);
        s2 = lt1 ? s1 : (lt2 ? d  : s2); i2 = lt1 ? i1 : (lt2 ? id : i2);
        s1 = lt0 ? s0 : (lt1 ? d  : s1); i1 = lt0 ? i0 : (lt1 ? id : i1);
        s0 = lt0 ? d  : s0;              i0 = lt0 ? id : i0;
    }
    float cx = corners[(size_t)f*3+0], cy = corners[(size_t)f*3+1], cz = corners[(size_t)f*3+2];
    int ii[3] = {i0, i1, i2};
    float w[3];
    #pragma unroll
    for (int j = 0; j < 3; ++j) {
        const float* pp = xyz + ((size_t)b*NPTS + ii[j])*3;
        float dx = pp[0]-cx, dy = pp[1]-cy, dz = pp[2]-cz;
        float dist = sqrtf((dx*dx + dy*dy) + dz*dz);
        w[j] = 1.0f/(dist + 1e-8f);
    }
    float wsum = (w[0]+w[1])+w[2];
    #pragma unroll
    for (int j = 0; j < 3; ++j) {
        idx3[(size_t)f*3+j] = ii[j];
        w3[(size_t)f*3+j]   = w[j]/wsum;
    }
}

/* ---------------- interp features + build feat [b][m][131] ---------------- */
__global__ __launch_bounds__(256) void k_interp(const float* __restrict__ featT, const float* __restrict__ rel,
                         const int* __restrict__ idx3, const float* __restrict__ w3,
                         float* __restrict__ feat)
{
    int t = threadIdx.x; int cc = t >> 7, c = t & 127;
    for (int it = 0; it < 4; ++it) {
        int g = blockIdx.x*8 + it*2 + cc;      /* 0..16383 */
        int b = g >> 13;
        const int*   ip = idx3 + (size_t)g*3;
        const float* wp = w3   + (size_t)g*3;
        int j0 = ip[0], j1 = ip[1], j2 = ip[2];
        float w0 = wp[0], w1 = wp[1], w2 = wp[2];
        const float* fb = featT + (size_t)b*NPTS*CH_F;
        float v = (fb[(size_t)j0*CH_F + c]*w0 + fb[(size_t)j1*CH_F + c]*w1) + fb[(size_t)j2*CH_F + c]*w2;
        float* fr = feat + (size_t)g*FEAT_C;
        fr[3+c] = v;
        if (c < 3) fr[c] = rel[(size_t)g*3 + c];
    }
}

/* ------------- fused MLP1 -> MLP2 -> maxpool(K) per (b,p) ------------- */
__global__ __launch_bounds__(256) void k_mlp(const float* __restrict__ feat,
        const float* __restrict__ w1t, const float* __restrict__ b1,
        const float* __restrict__ w2t, const float* __restrict__ b2,
        float* __restrict__ h2max)
{
    __shared__ float lds[FEAT_C*64];          /* 33.5 KB, reused for h1 [128][64] */
    int blk = blockIdx.x; int b = blk >> 7, p = blk & 127;
    int t = threadIdx.x;

    const float4* src = (const float4*)(feat + (((size_t)b*MTOT) + (size_t)p*64)*FEAT_C);
    for (int i = t; i < (FEAT_C*64)/4; i += 256) {
        float4 v = src[i];
        int fl = i*4;
        #pragma unroll
        for (int j = 0; j < 4; ++j) {
            float vv = (j==0) ? v.x : (j==1) ? v.y : (j==2) ? v.z : v.w;
            int f2 = fl + j;
            int mm = f2 / FEAT_C;
            int ccx = f2 - mm*FEAT_C;
            lds[ccx*64 + mm] = vv;            /* store transposed: [c][m] */
        }
    }
    __syncthreads();

    int og = t >> 3, mg = t & 7;              /* phase1: o = og*4+i, m = mg*8+j */
    float acc[4][8];
    #pragma unroll
    for (int i = 0; i < 4; ++i) { float bb = b1[og*4+i];
        #pragma unroll
        for (int j = 0; j < 8; ++j) acc[i][j] = bb; }
    #pragma unroll 4
    for (int c = 0; c < FEAT_C; ++c) {
        float4 wv = *(const float4*)(w1t + c*128 + og*4);
        float4 f0 = *(const float4*)(&lds[c*64 + mg*8]);
        float4 f1 = *(const float4*)(&lds[c*64 + mg*8 + 4]);
        float fv[8] = {f0.x,f0.y,f0.z,f0.w,f1.x,f1.y,f1.z,f1.w};
        float wa[4] = {wv.x,wv.y,wv.z,wv.w};
        #pragma unroll
        for (int i = 0; i < 4; ++i)
            #pragma unroll
            for (int j = 0; j < 8; ++j)
                acc[i][j] = fmaf(wa[i], fv[j], acc[i][j]);
    }
    __syncthreads();                           /* all feat reads done */
    #pragma unroll
    for (int i = 0; i < 4; ++i) {
        float4 r0 = make_float4(fmaxf(acc[i][0],0.f), fmaxf(acc[i][1],0.f), fmaxf(acc[i][2],0.f), fmaxf(acc[i][3],0.f));
        float4 r1 = make_float4(fmaxf(acc[i][4],0.f), fmaxf(acc[i][5],0.f), fmaxf(acc[i][6],0.f), fmaxf(acc[i][7],0.f));
        *(float4*)(&lds[(og*4+i)*64 + mg*8])     = r0;
        *(float4*)(&lds[(og*4+i)*64 + mg*8 + 4]) = r1;
    }
    __syncthreads();

    /* phase2: o2 = og*8+i (256 outs), same m slots */
    float a2[8][8];
    #pragma unroll
    for (int i = 0; i < 8; ++i) { float bb = b2[og*8+i];
        #pragma unroll
        for (int j = 0; j < 8; ++j) a2[i][j] = bb; }
    #pragma unroll 2
    for (int c = 0; c < 128; ++c) {
        float4 wv0 = *(const float4*)(w2t + c*MLP2_C + og*8);
        float4 wv1 = *(const float4*)(w2t + c*MLP2_C + og*8 + 4);
        float4 f0 = *(const float4*)(&lds[c*64 + mg*8]);
        float4 f1 = *(const float4*)(&lds[c*64 + mg*8 + 4]);
        float fv[8] = {f0.x,f0.y,f0.z,f0.w,f1.x,f1.y,f1.z,f1.w};
        float wa[8] = {wv0.x,wv0.y,wv0.z,wv0.w,wv1.x,wv1.y,wv1.z,wv1.w};
        #pragma unroll
        for (int i = 0; i < 8; ++i)
            #pragma unroll
            for (int j = 0; j < 8; ++j)
                a2[i][j] = fmaf(wa[i], fv[j], a2[i][j]);
    }
    float mx[8];
    #pragma unroll
    for (int i = 0; i < 8; ++i) {
        float m0 = a2[i][0];
        #pragma unroll
        for (int j = 1; j < 8; ++j) m0 = fmaxf(m0, a2[i][j]);
        mx[i] = fmaxf(m0, 0.0f);               /* relu then max == max then relu */
    }
    #pragma unroll
    for (int off = 1; off < 8; off <<= 1)
        #pragma unroll
        for (int i = 0; i < 8; ++i)
            mx[i] = fmaxf(mx[i], __shfl_xor(mx[i], off, 64));
    if (mg == 0) {
        #pragma unroll
        for (int i = 0; i < 8; ++i)
            h2max[((size_t)b*MLP2_C + og*8 + i)*NPOINT + p] = mx[i];
    }
}

/* ---------------- IoU head ---------------- */
__global__ void k_gemm0(const float* __restrict__ h2, const float* __restrict__ w0,
                        const float* __restrict__ b0, float* __restrict__ x0)
{
    int f = blockIdx.x*256 + threadIdx.x;
    int b = f >> 14, o = (f >> 7) & 127, p = f & 127;
    const float* hb = h2 + (size_t)b*MLP2_C*NPOINT + p;
    const float* wr = w0 + o*MLP2_C;
    float acc = b0[o];
    #pragma unroll 4
    for (int c = 0; c < MLP2_C; ++c) acc = fmaf(wr[c], hb[(size_t)c*NPOINT], acc);
    x0[f] = acc;
}

__global__ void k_bnstats(const float* __restrict__ x, const float* __restrict__ g,
                          const float* __restrict__ be, float* __restrict__ sc_sh)
{
    int o = threadIdx.x;   /* 128 */
    float s = 0.f, ss = 0.f;
    for (int b = 0; b < BSZ; ++b)
        for (int p = 0; p < NPOINT; ++p) {
            float v = x[((size_t)b*128 + o)*NPOINT + p];
            s += v; ss += v*v;
        }
    float mean = s * (1.0f/256.0f);
    float var  = ss * (1.0f/256.0f) - mean*mean;
    if (var < 0.f) var = 0.f;
    float scale = g[o] / sqrtf(var + 1e-5f);
    sc_sh[o]       = scale;
    sc_sh[128 + o] = be[o] - mean*scale;
}

__global__ void k_gemm1(const float* __restrict__ x0, const float* __restrict__ bn0,
                        const float* __restrict__ w1, const float* __restrict__ b1,
                        float* __restrict__ x1)
{
    int f = blockIdx.x*256 + threadIdx.x;
    int b = f >> 14, o = (f >> 7) & 127, p = f & 127;
    const float* xb = x0 + (size_t)b*128*NPOINT + p;
    const float* wr = w1 + o*128;
    float acc = b1[o];
    #pragma unroll 4
    for (int c = 0; c < 128; ++c) {
        float v = fmaxf(fmaf(xb[(size_t)c*NPOINT], bn0[c], bn0[128+c]), 0.0f);
        acc = fmaf(wr[c], v, acc);
    }
    x1[f] = acc;
}

__global__ void k_final(const float* __restrict__ x1, const float* __restrict__ bn1,
                        const float* __restrict__ w2, const float* __restrict__ b2,
                        float* __restrict__ out)
{
    int t = threadIdx.x;  /* 256 */
    int b = t >> 7, p = t & 127;
    float acc = b2[0];
    #pragma unroll 4
    for (int c = 0; c < 128; ++c) {
        float v = fmaxf(fmaf(x1[((size_t)b*128 + c)*NPOINT + p], bn1[c], bn1[128+c]), 0.0f);
        acc = fmaf(w2[c], v, acc);
    }
    out[b*NPOINT + p] = acc;
}

extern "C" void kernel_launch(void* const* d_in, const int* in_sizes, int n_in,
                              void* d_out, int out_size, void* d_ws, size_t ws_size,
                              hipStream_t stream)
{
    const float* xyz   = (const float*)d_in[0];
    const float* ofeat = (const float*)d_in[1];
    const float* cand  = (const float*)d_in[2];
    /* d_in[3] = pred_cls, unused by the reference forward */
    const float* offs  = (const float*)d_in[4];
    const float* angc  = (const float*)d_in[5];
    const float* angr  = (const float*)d_in[6];
    const float* w1    = (const float*)d_in[7];
    const float* b1    = (const float*)d_in[8];
    const float* w2    = (const float*)d_in[9];
    const float* b2    = (const float*)d_in[10];
    const float* wi0   = (const float*)d_in[11];
    const float* bi0   = (const float*)d_in[12];
    const float* gi0   = (const float*)d_in[13];
    const float* bei0  = (const float*)d_in[14];
    const float* wi1   = (const float*)d_in[15];
    const float* bi1   = (const float*)d_in[16];
    const float* gi1   = (const float*)d_in[17];
    const float* bei1  = (const float*)d_in[18];
    const float* wi2   = (const float*)d_in[19];
    const float* bi2   = (const float*)d_in[20];

    char* ws = (char*)d_ws;
    float* corners = (float*)(ws + OFF_CORNERS);
    float* rel     = (float*)(ws + OFF_REL);
    float* pd      = (float*)(ws + OFF_PD);
    int*   pix     = (int*)  (ws + OFF_PI);
    int*   idx3    = (int*)  (ws + OFF_IDX);
    float* w3      = (float*)(ws + OFF_W3);
    float* featT   = (float*)(ws + OFF_FEATT);
    float* feat    = (float*)(ws + OFF_FEAT);
    float* w1t     = (float*)(ws + OFF_W1T);
    float* w2t     = (float*)(ws + OFF_W2T);
    float* h2      = (float*)(ws + OFF_H2);
    float* x0      = (float*)(ws + OFF_X0);
    float* x1      = (float*)(ws + OFF_X1);
    float* bn0     = (float*)(ws + OFF_BN0);
    float* bn1     = (float*)(ws + OFF_BN1);

    k_decode   <<<1, 256, 0, stream>>>(cand, offs, angc, angr, corners, rel);
    k_prepw    <<<64, 256, 0, stream>>>(w1, w2, w1t, w2t);
    k_transpose<<<dim3(128,2), 256, 0, stream>>>(ofeat, featT);
    k_three_nn <<<dim3(32,8,2), 256, 0, stream>>>(xyz, corners, pd, pix);
    k_merge    <<<64, 256, 0, stream>>>(xyz, corners, pd, pix, idx3, w3);
    k_interp   <<<2048, 256, 0, stream>>>(featT, rel, idx3, w3, feat);
    k_mlp      <<<256, 256, 0, stream>>>(feat, w1t, b1, w2t, b2, h2);
    k_gemm0    <<<128, 256, 0, stream>>>(h2, wi0, bi0, x0);
    k_bnstats  <<<1, 128, 0, stream>>>(x0, gi0, bei0, bn0);
    k_gemm1    <<<128, 256, 0, stream>>>(x0, bn0, wi1, bi1, x1);
    k_bnstats  <<<1, 128, 0, stream>>>(x1, gi1, bei1, bn1);
    k_final    <<<1, 256, 0, stream>>>(x1, bn1, wi2, bi2, (float*)d_out);
}